// Round 4
// baseline (92.059 us; speedup 1.0000x reference)
//
#include <hip/hip_runtime.h>
#include <math.h>

#define EPS2f 0.25f
#define EPS4f 0.0625f

// ---------------------------------------------------------------------------
// Kernel 1: precompute per-(ij,k) tables (layouts unchanged from round 3).
//   AB4[k2*1024 + ij] = float4{ A(2k2), B2(2k2), A(2k2+1), B2(2k2+1) }
//   KV [ij*64 + k]    = float2{ K, Vm }
//   C0 [ij]           = sum_k ( mu_t^2/Sigma + log(Sigma) )
// ---------------------------------------------------------------------------
__global__ __launch_bounds__(256) void precomp_kernel(
    const float* __restrict__ Mu0, const float* __restrict__ Mu1,
    const float* __restrict__ S0,  const float* __restrict__ S1,
    const float* __restrict__ tptr,
    float2* __restrict__ AB4, float2* __restrict__ KV,
    float* __restrict__ C0)
{
    const int tid = threadIdx.x;
    const int k   = tid & 63;
    const int ij  = (blockIdx.x << 2) + (tid >> 6);
    const int i   = ij >> 5;              // N0=32
    const int j   = ij & 31;              // N1=32
    const float t   = *tptr;
    const float omt = 1.0f - t;

    const float s0 = S0[i * 64 + k];
    const float s1 = S1[j * 64 + k];
    const float m0 = Mu0[i * 64 + k];
    const float m1 = Mu1[j * 64 + k];

    const float ds  = sqrtf(4.0f * s0 * s1 + EPS4f);
    const float cs  = 0.5f * (ds - EPS2f);
    const float mt  = omt * m0 + t * m1;
    const float sig = omt * omt * s0 + t * t * s1
                    + 2.0f * t * omt * (cs + 0.5f * EPS2f);
    const float isig = 1.0f / sig;
    const float st = t * s1 - omt * s0 + (omt - t) * cs - EPS2f * t;
    const float kk = st * isig;
    const float v  = m1 - m0;

    AB4[((k >> 1) << 11) + (ij << 1) + (k & 1)] = make_float2(isig, 2.0f * mt * isig);
    KV[(ij << 6) + k] = make_float2(kk, v - kk * mt);

    float c = mt * mt * isig + __logf(sig);
    #pragma unroll
    for (int off = 32; off >= 1; off >>= 1)
        c += __shfl_xor(c, off, 64);
    if (k == 0) C0[ij] = c;
}

// ---------------------------------------------------------------------------
// Kernel 2: main. Block = (ij-quarter q, batch-chunk c of 16 rows).
// Grid 256 = 4 quarters x 64 chunks. 1024 threads = 16 waves.
//   Phase A (tid<256): thread = ij_local, 16 batch-row accumulators;
//     each AB table element is reused 16x in registers. W -> LDS Wl[ij][16].
//   Phase B: wave w handles ij [w*16, w*16+16), lane = k, 16 num accums.
//   Epilogue: wave w = batch-row bb; combine 16 waves' partials; write
//     per-(quarter) partial num/den to ws; finalize kernel reduces quarters.
// Table traffic: 256 KB/block * 256 blocks = 64 MB (4x less than round 3).
// ---------------------------------------------------------------------------
__global__ __launch_bounds__(1024, 4) void gmm_main_kernel(
    const float* __restrict__ X,   const float* __restrict__ Lam,
    const float* __restrict__ C0,
    const float4* __restrict__ AB4, const float2* __restrict__ KV,
    float* __restrict__ pnum, float* __restrict__ pden)
{
    __shared__ float Xs[64 * 20];     // [k][bb], rows padded to 20 (16B-aligned)
    __shared__ float XsT2[16 * 64];   // [bb][k] for phase-B per-lane reads
    __shared__ float Wl[256 * 20];    // [ij_l][bb], rows padded to 20
    __shared__ float red[16 * 64 * 17]; // [w][k][bb] pad 17: conflict-free

    const int tid  = threadIdx.x;
    const int lane = tid & 63;
    const int w    = tid >> 6;        // 0..15
    const int q    = blockIdx.x & 3;  // ij quarter; same-q blocks share XCDs
    const int c    = blockIdx.x >> 2; // batch chunk (16 rows)

    // ---- Stage X rows [c*16, c*16+16) in two layouts ----
    {
        const int bb = w;             // 16 rows
        const float xv = X[(c * 16 + bb) * 64 + lane];   // coalesced
        Xs[lane * 20 + bb]  = xv;     // stride-20: 2-way aliasing only
        XsT2[bb * 64 + lane] = xv;
    }
    __syncthreads();

    // ---- Phase A: 256 threads, one ij each, 16 batch rows in registers ----
    if (tid < 256) {
        const int ij_l = tid;
        const int ij_g = (q << 8) + ij_l;
        float acc[16];
        #pragma unroll
        for (int bb = 0; bb < 16; ++bb) acc[bb] = 0.f;

        #pragma unroll 4
        for (int k2 = 0; k2 < 32; ++k2) {
            const float4 ab = AB4[(k2 << 10) + ij_g];    // coalesced 16B/lane
            const float4* xr0 = (const float4*)&Xs[(2 * k2) * 20];     // bcast
            const float4* xr1 = (const float4*)&Xs[(2 * k2 + 1) * 20]; // bcast
            #pragma unroll
            for (int g = 0; g < 4; ++g) {
                const float4 x0 = xr0[g];
                const float4 x1 = xr1[g];
                acc[4*g+0] = fmaf(fmaf(ab.x, x0.x, -ab.y), x0.x, acc[4*g+0]);
                acc[4*g+1] = fmaf(fmaf(ab.x, x0.y, -ab.y), x0.y, acc[4*g+1]);
                acc[4*g+2] = fmaf(fmaf(ab.x, x0.z, -ab.y), x0.z, acc[4*g+2]);
                acc[4*g+3] = fmaf(fmaf(ab.x, x0.w, -ab.y), x0.w, acc[4*g+3]);
                acc[4*g+0] = fmaf(fmaf(ab.z, x1.x, -ab.w), x1.x, acc[4*g+0]);
                acc[4*g+1] = fmaf(fmaf(ab.z, x1.y, -ab.w), x1.y, acc[4*g+1]);
                acc[4*g+2] = fmaf(fmaf(ab.z, x1.z, -ab.w), x1.z, acc[4*g+2]);
                acc[4*g+3] = fmaf(fmaf(ab.z, x1.w, -ab.w), x1.w, acc[4*g+3]);
            }
        }

        const float c0v = C0[ij_g];
        const float lm  = Lam[ij_g];
        float4* wrow = (float4*)&Wl[ij_l * 20];
        #pragma unroll
        for (int g = 0; g < 4; ++g) {
            float4 wv;
            wv.x = __expf(fminf(fmaxf(-0.5f * (acc[4*g+0] + c0v), -50.0f), 50.0f)) * lm;
            wv.y = __expf(fminf(fmaxf(-0.5f * (acc[4*g+1] + c0v), -50.0f), 50.0f)) * lm;
            wv.z = __expf(fminf(fmaxf(-0.5f * (acc[4*g+2] + c0v), -50.0f), 50.0f)) * lm;
            wv.w = __expf(fminf(fmaxf(-0.5f * (acc[4*g+3] + c0v), -50.0f), 50.0f)) * lm;
            wrow[g] = wv;
        }
    }
    __syncthreads();

    // ---- Phase B: wave w handles ij_l in [w*16, w*16+16), lane = k ----
    float xk[16];
    #pragma unroll
    for (int bb = 0; bb < 16; ++bb) xk[bb] = XsT2[bb * 64 + lane];
    float n[16];
    #pragma unroll
    for (int bb = 0; bb < 16; ++bb) n[bb] = 0.f;

    const int ijb0 = w << 4;
    #pragma unroll 4
    for (int cc = 0; cc < 16; ++cc) {
        const int ij_l = ijb0 + cc;
        const float2 kv = KV[(((q << 8) + ij_l) << 6) + lane]; // coalesced 512B
        const float4* wrow = (const float4*)&Wl[ij_l * 20];    // broadcast
        #pragma unroll
        for (int g = 0; g < 4; ++g) {
            const float4 wv = wrow[g];
            float u;
            u = fmaf(kv.x, xk[4*g+0], kv.y); n[4*g+0] = fmaf(wv.x, u, n[4*g+0]);
            u = fmaf(kv.x, xk[4*g+1], kv.y); n[4*g+1] = fmaf(wv.y, u, n[4*g+1]);
            u = fmaf(kv.x, xk[4*g+2], kv.y); n[4*g+2] = fmaf(wv.z, u, n[4*g+2]);
            u = fmaf(kv.x, xk[4*g+3], kv.y); n[4*g+3] = fmaf(wv.w, u, n[4*g+3]);
        }
    }
    #pragma unroll
    for (int bb = 0; bb < 16; ++bb)
        red[(w * 64 + lane) * 17 + bb] = n[bb];   // stride-17: conflict-free
    __syncthreads();

    // ---- Epilogue: wave w <-> batch row bb = w ----
    {
        const int bb = w;
        float s = 0.f;
        #pragma unroll
        for (int ww = 0; ww < 16; ++ww)
            s += red[(ww * 64 + lane) * 17 + bb];
        pnum[((((q << 6) + c) << 4) + bb) * 64 + lane] = s;   // coalesced

        // den partial for this quarter: sum W over 256 ij (one-time LDS reads)
        float d = Wl[lane * 20 + bb]        + Wl[(lane + 64) * 20 + bb]
                + Wl[(lane + 128) * 20 + bb] + Wl[(lane + 192) * 20 + bb];
        #pragma unroll
        for (int off = 32; off >= 1; off >>= 1)
            d += __shfl_xor(d, off, 64);
        if (lane == 0) pden[((q << 6) + c) * 16 + bb] = d;
    }
}

// ---------------------------------------------------------------------------
// Kernel 3: combine the 4 ij-quarter partials, divide, store.
// ---------------------------------------------------------------------------
__global__ __launch_bounds__(1024) void finalize_kernel(
    const float* __restrict__ pnum, const float* __restrict__ pden,
    float* __restrict__ out)
{
    const int idx = blockIdx.x * 1024 + threadIdx.x;  // [0, 65536)
    const int k   = idx & 63;
    const int b   = idx >> 6;         // [0, 1024)
    const int c   = b >> 4;
    const int bb  = b & 15;
    float s = 0.f, d = 0.f;
    #pragma unroll
    for (int qq = 0; qq < 4; ++qq) {
        s += pnum[((((qq << 6) + c) << 4) + bb) * 64 + k];
        d += pden[((qq << 6) + c) * 16 + bb];
    }
    out[idx] = s / d;
}

extern "C" void kernel_launch(void* const* d_in, const int* in_sizes, int n_in,
                              void* d_out, int out_size, void* d_ws, size_t ws_size,
                              hipStream_t stream) {
    const float* X   = (const float*)d_in[0];
    const float* Mu0 = (const float*)d_in[1];
    const float* Mu1 = (const float*)d_in[2];
    const float* S0  = (const float*)d_in[3];
    const float* S1  = (const float*)d_in[4];
    const float* Lam = (const float*)d_in[5];
    const float* t   = (const float*)d_in[6];
    float* out = (float*)d_out;

    char* ws = (char*)d_ws;
    float2* AB4 = (float2*)(ws);                       // 512 KiB
    float2* KV  = (float2*)(ws + (512 << 10));         // 512 KiB
    float*  C0  = (float*)(ws + (1024 << 10));         // 4 KiB
    float*  pden = (float*)(ws + (1024 << 10) + (16 << 10));  // 16 KiB
    float*  pnum = (float*)(ws + (1024 << 10) + (64 << 10));  // 1 MiB

    precomp_kernel<<<256, 256, 0, stream>>>(Mu0, Mu1, S0, S1, t, AB4, KV, C0);
    gmm_main_kernel<<<256, 1024, 0, stream>>>(X, Lam, C0, (const float4*)AB4, KV,
                                              pnum, pden);
    finalize_kernel<<<64, 1024, 0, stream>>>(pnum, pden, out);
}